// Round 10
// baseline (402.365 us; speedup 1.0000x reference)
//
#include <hip/hip_runtime.h>
#include <math.h>

#define NN 50000
#define GG 50
#define NODE 1000
#define EE 320000
#define HEADS 4

typedef __attribute__((ext_vector_type(8))) short short8;
typedef __attribute__((ext_vector_type(8))) __bf16 bf16x8;
typedef __attribute__((ext_vector_type(4))) float f32x4;

__device__ __forceinline__ unsigned short f2bf(float f) {
    unsigned int u = __float_as_uint(f);
    u = (u + 0x7fffu + ((u >> 16) & 1u)) >> 16;
    return (unsigned short)u;
}
__device__ __forceinline__ float bf2f(unsigned short s) {
    return __uint_as_float(((unsigned int)s) << 16);
}

// ---------------- dtype conversion kernels ----------------
__global__ void cvt_f32_bf16(const float* __restrict__ in, unsigned short* __restrict__ outp, int n4) {
    int i = blockIdx.x * 256 + threadIdx.x;
    if (i < n4) {
        float4 f = *(const float4*)(in + (size_t)i * 4);
        ushort4 o;
        o.x = f2bf(f.x); o.y = f2bf(f.y); o.z = f2bf(f.z); o.w = f2bf(f.w);
        *(ushort4*)(outp + (size_t)i * 4) = o;
    }
}

// W[K][N] fp32 -> Wt[N][K] bf16
__global__ void wt_cvt(const float* __restrict__ W, unsigned short* __restrict__ Wt, int K, int N_) {
    int i = blockIdx.x * 256 + threadIdx.x;
    if (i < K * N_) {
        int n = i / K, k = i - n * K;
        Wt[i] = f2bf(W[(size_t)k * N_ + n]);
    }
}

// ---------------- CSR build ----------------
__global__ void count_deg(const int* __restrict__ dst, int* __restrict__ deg, int E_) {
    int i = blockIdx.x * 256 + threadIdx.x;
    if (i < E_) atomicAdd(&deg[dst[i]], 1);
}

__global__ void scan1(const int* __restrict__ deg, int* __restrict__ bsum, int Nn) {
    __shared__ int sh[256];
    int i = blockIdx.x * 256 + threadIdx.x;
    sh[threadIdx.x] = (i < Nn) ? deg[i] : 0;
    __syncthreads();
    for (int s = 128; s > 0; s >>= 1) {
        if (threadIdx.x < s) sh[threadIdx.x] += sh[threadIdx.x + s];
        __syncthreads();
    }
    if (threadIdx.x == 0) bsum[blockIdx.x] = sh[0];
}

__global__ void scan2(int* __restrict__ bsum, int nb, int* __restrict__ rowptr, int Nn, int E_) {
    if (threadIdx.x == 0 && blockIdx.x == 0) {
        int acc = 0;
        for (int i = 0; i < nb; ++i) { int v = bsum[i]; bsum[i] = acc; acc += v; }
        rowptr[Nn] = E_;
    }
}

__global__ void scan3(const int* __restrict__ deg, const int* __restrict__ bsum,
                      int* __restrict__ rowptr, int* __restrict__ cursor, int Nn) {
    __shared__ int sh[256];
    int i = blockIdx.x * 256 + threadIdx.x;
    int v = (i < Nn) ? deg[i] : 0;
    sh[threadIdx.x] = v;
    __syncthreads();
    for (int s = 1; s < 256; s <<= 1) {
        int t = (threadIdx.x >= s) ? sh[threadIdx.x - s] : 0;
        __syncthreads();
        sh[threadIdx.x] += t;
        __syncthreads();
    }
    if (i < Nn) {
        int ex = sh[threadIdx.x] - v + bsum[blockIdx.x];
        rowptr[i] = ex;
        cursor[i] = ex;
    }
}

// store src node id directly in CSR slot (removes one indirection in the hot loop)
__global__ void scatter_edges(const int* __restrict__ src, const int* __restrict__ dst,
                              int* __restrict__ cursor, int* __restrict__ csrc, int E_) {
    int i = blockIdx.x * 256 + threadIdx.x;
    if (i < E_) { int pos = atomicAdd(&cursor[dst[i]], 1); csrc[pos] = src[i]; }
}

// ---------------- bf16 MFMA GEMM, bf16 output ----------------
// C[M,Ncols](bf16) = A[M,K](bf16) @ Wt[Ncols,K](bf16)^T + bias
template<int K>
__global__ __launch_bounds__(256)
void gemm_mfma(const unsigned short* __restrict__ A, const unsigned short* __restrict__ Wt,
               const float* __restrict__ bias, unsigned short* __restrict__ C,
               int M, int Ncols) {
    __shared__ short A_lds[128 * K];
    __shared__ short B_lds[128 * K];
    constexpr int CH = K / 8;          // 16B chunks per row
    constexpr int ROWB = K * 2;        // bytes per LDS row
    int tid = threadIdx.x;
    int lane = tid & 63, wave = tid >> 6;
    int row0 = blockIdx.y * 128, col0 = blockIdx.x * 128;

    for (int c = tid; c < 128 * CH; c += 256) {
        int r = c / CH, kc = c - r * CH;
        int gr = row0 + r; if (gr >= M) gr = M - 1;
        short8 v = *(const short8*)(A + (size_t)gr * K + kc * 8);
        *(short8*)((char*)A_lds + r * ROWB + ((kc * 16) ^ ((r & 7) << 4))) = v;
    }
    for (int c = tid; c < 128 * CH; c += 256) {
        int r = c / CH, kc = c - r * CH;
        short8 v = *(const short8*)(Wt + (size_t)(col0 + r) * K + kc * 8);
        *(short8*)((char*)B_lds + r * ROWB + ((kc * 16) ^ ((r & 7) << 4))) = v;
    }
    __syncthreads();

    int wr = wave >> 1, wc = wave & 1;
    f32x4 acc[4][4] = {};
    #pragma unroll
    for (int ks = 0; ks < K / 32; ++ks) {
        int kbyte = ks * 64 + ((lane >> 4) << 4);
        short8 a[4], b[4];
        #pragma unroll
        for (int m = 0; m < 4; ++m) {
            int r = wr * 64 + m * 16 + (lane & 15);
            a[m] = *(const short8*)((const char*)A_lds + r * ROWB + (kbyte ^ ((r & 7) << 4)));
        }
        #pragma unroll
        for (int n = 0; n < 4; ++n) {
            int r = wc * 64 + n * 16 + (lane & 15);
            b[n] = *(const short8*)((const char*)B_lds + r * ROWB + (kbyte ^ ((r & 7) << 4)));
        }
        #pragma unroll
        for (int m = 0; m < 4; ++m)
            #pragma unroll
            for (int n = 0; n < 4; ++n)
                acc[m][n] = __builtin_amdgcn_mfma_f32_16x16x32_bf16(
                    __builtin_bit_cast(bf16x8, a[m]), __builtin_bit_cast(bf16x8, b[n]),
                    acc[m][n], 0, 0, 0);
    }

    // epilogue: D mapping col=lane&15, row=(lane>>4)*4+q ; write bf16
    #pragma unroll
    for (int m = 0; m < 4; ++m) {
        int grb = row0 + wr * 64 + m * 16 + ((lane >> 4) << 2);
        #pragma unroll
        for (int q = 0; q < 4; ++q) {
            int gr = grb + q;
            if (gr < M) {
                #pragma unroll
                for (int n = 0; n < 4; ++n) {
                    int gc = col0 + wc * 64 + n * 16 + (lane & 15);
                    C[(size_t)gr * Ncols + gc] = f2bf(acc[m][n][q] + bias[gc]);
                }
            }
        }
    }
}

// ---------------- fused GATv2 edge phase: one wave per dst node (grid-stride) ----------------
// 2-edge paired pipeline: pair (j,j+1) rows are live while pair (j+2,j+3) loads are in
// flight -> up to 4 independent L2 gathers per wave. Defer-max online softmax (THR=8).
// Lane map: head = lane>>4, dims (lane&15)*VE .. +VE-1.
// D=64 -> hout bf16 [NN][64]; D=128 -> hout f32 [NN][128]
template<int D>
__global__ __launch_bounds__(256)
void gat_fused(const int* __restrict__ rowptr, const int* __restrict__ csrc,
               const unsigned short* __restrict__ fs, const unsigned short* __restrict__ fd,
               const float* __restrict__ attn, void* __restrict__ hout, int Nn) {
    constexpr int VE = D / 16;
    constexpr int HD = HEADS * D;
    int lane = threadIdx.x & 63;
    int wave = (blockIdx.x * blockDim.x + threadIdx.x) >> 6;
    int nw = (gridDim.x * blockDim.x) >> 6;
    int head = lane >> 4;
    int doff = (lane & 15) * VE;

    float at[VE];
    #pragma unroll
    for (int j = 0; j < VE; ++j) at[j] = attn[head * D + doff + j];

    for (int n = wave; n < Nn; n += nw) {
        int b = rowptr[n], e_ = rowptr[n + 1];
        float r[VE];
        if (b == e_) {
            #pragma unroll
            for (int k = 0; k < VE; ++k) r[k] = 0.f;
        } else {
            // fd row chunk (once per node)
            float fdf[VE];
            if constexpr (VE == 4) {
                ushort4 vd = *(const ushort4*)(fd + (size_t)n * HD + lane * 4);
                fdf[0] = bf2f(vd.x); fdf[1] = bf2f(vd.y); fdf[2] = bf2f(vd.z); fdf[3] = bf2f(vd.w);
            } else {
                short8 vd = *(const short8*)(fd + (size_t)n * HD + lane * 8);
                #pragma unroll
                for (int k = 0; k < 8; ++k) fdf[k] = bf2f((unsigned short)vd[k]);
            }
            float m = -INFINITY, l = 0.f;
            float acc[VE];
            #pragma unroll
            for (int k = 0; k < VE; ++k) acc[k] = 0.f;

            // paired pipeline buffers
            ushort4 c40 = {}, c41 = {}, p40 = {}, p41 = {};
            short8  c80 = {}, c81 = {}, p80 = {}, p81 = {};
            if constexpr (VE == 4) {
                c40 = *(const ushort4*)(fs + (size_t)csrc[b] * HD + lane * 4);
                if (b + 1 < e_) c41 = *(const ushort4*)(fs + (size_t)csrc[b + 1] * HD + lane * 4);
            } else {
                c80 = *(const short8*)(fs + (size_t)csrc[b] * HD + lane * 8);
                if (b + 1 < e_) c81 = *(const short8*)(fs + (size_t)csrc[b + 1] * HD + lane * 8);
            }

            for (int j = b; j < e_; j += 2) {
                bool two = (j + 1 < e_);
                // prefetch pair j+2 / j+3
                if (j + 2 < e_) {
                    int sn = csrc[j + 2];
                    if constexpr (VE == 4) p40 = *(const ushort4*)(fs + (size_t)sn * HD + lane * 4);
                    else                   p80 = *(const short8*)(fs + (size_t)sn * HD + lane * 8);
                }
                if (j + 3 < e_) {
                    int sn = csrc[j + 3];
                    if constexpr (VE == 4) p41 = *(const ushort4*)(fs + (size_t)sn * HD + lane * 4);
                    else                   p81 = *(const short8*)(fs + (size_t)sn * HD + lane * 8);
                }
                // unpack current pair
                float fs0[VE], fs1[VE];
                if constexpr (VE == 4) {
                    fs0[0] = bf2f(c40.x); fs0[1] = bf2f(c40.y); fs0[2] = bf2f(c40.z); fs0[3] = bf2f(c40.w);
                    fs1[0] = bf2f(c41.x); fs1[1] = bf2f(c41.y); fs1[2] = bf2f(c41.z); fs1[3] = bf2f(c41.w);
                } else {
                    #pragma unroll
                    for (int k = 0; k < 8; ++k) fs0[k] = bf2f((unsigned short)c80[k]);
                    #pragma unroll
                    for (int k = 0; k < 8; ++k) fs1[k] = bf2f((unsigned short)c81[k]);
                }
                // independent logit computations
                float p0 = 0.f, p1 = 0.f;
                #pragma unroll
                for (int k = 0; k < VE; ++k) {
                    float v0 = fs0[k] + fdf[k];
                    v0 = v0 >= 0.f ? v0 : 0.2f * v0;
                    p0 += v0 * at[k];
                    float v1 = fs1[k] + fdf[k];
                    v1 = v1 >= 0.f ? v1 : 0.2f * v1;
                    p1 += v1 * at[k];
                }
                p0 += __shfl_xor(p0, 1); p1 += __shfl_xor(p1, 1);
                p0 += __shfl_xor(p0, 2); p1 += __shfl_xor(p1, 2);
                p0 += __shfl_xor(p0, 4); p1 += __shfl_xor(p1, 4);
                p0 += __shfl_xor(p0, 8); p1 += __shfl_xor(p1, 8);
                // defer-max online softmax (THR=8); first iter self-initializes (m=-inf -> sc=0)
                float pm = two ? fmaxf(p0, p1) : p0;
                if (__any(pm > m + 8.f)) {
                    float mn = fmaxf(m, pm);
                    float sc = __expf(m - mn);
                    l *= sc;
                    #pragma unroll
                    for (int k = 0; k < VE; ++k) acc[k] *= sc;
                    m = mn;
                }
                float w0 = __expf(p0 - m);
                l += w0;
                #pragma unroll
                for (int k = 0; k < VE; ++k) acc[k] += w0 * fs0[k];
                if (two) {
                    float w1 = __expf(p1 - m);
                    l += w1;
                    #pragma unroll
                    for (int k = 0; k < VE; ++k) acc[k] += w1 * fs1[k];
                }
                // rotate pipeline
                if constexpr (VE == 4) { c40 = p40; c41 = p41; }
                else                   { c80 = p80; c81 = p81; }
            }
            float inv = 1.f / l;
            #pragma unroll
            for (int k = 0; k < VE; ++k) r[k] = acc[k] * inv;
        }
        // head-max across the 4 head groups (lanes l, l^16, l^32, l^48)
        #pragma unroll
        for (int k = 0; k < VE; ++k) {
            r[k] = fmaxf(r[k], __shfl_xor(r[k], 16));
            r[k] = fmaxf(r[k], __shfl_xor(r[k], 32));
        }
        if (lane < 16) {
            if constexpr (VE == 4) {
                ushort4 o;
                o.x = f2bf(r[0]); o.y = f2bf(r[1]); o.z = f2bf(r[2]); o.w = f2bf(r[3]);
                *(ushort4*)((unsigned short*)hout + (size_t)n * 64 + doff) = o;
            } else {
                float* hp = (float*)hout + (size_t)n * 128 + doff;
                *(float4*)hp = make_float4(r[0], r[1], r[2], r[3]);
                *(float4*)(hp + 4) = make_float4(r[4], r[5], r[6], r[7]);
            }
        }
    }
}

// ---------------- global attention pooling: one block per graph ----------------
__global__ void pool_kernel(const float* __restrict__ h2, const float* __restrict__ gate_w,
                            const float* __restrict__ gate_b, float* __restrict__ out) {
    __shared__ float gate[NODE];
    __shared__ float red[256];
    int g = blockIdx.x;
    int tid = threadIdx.x;
    const float* hb = h2 + (size_t)g * NODE * 128;
    float gb = gate_b[0];
    for (int n = tid; n < NODE; n += 256) {
        const float* r = hb + (size_t)n * 128;
        float acc = 0.f;
        #pragma unroll 8
        for (int k = 0; k < 128; ++k) acc += r[k] * gate_w[k];
        gate[n] = acc + gb;
    }
    __syncthreads();
    float m = -INFINITY;
    for (int n = tid; n < NODE; n += 256) m = fmaxf(m, gate[n]);
    red[tid] = m;
    __syncthreads();
    for (int s = 128; s > 0; s >>= 1) {
        if (tid < s) red[tid] = fmaxf(red[tid], red[tid + s]);
        __syncthreads();
    }
    m = red[0];
    __syncthreads();
    float ssum = 0.f;
    for (int n = tid; n < NODE; n += 256) {
        float e = __expf(gate[n] - m);
        gate[n] = e;
        ssum += e;
    }
    red[tid] = ssum;
    __syncthreads();
    for (int s = 128; s > 0; s >>= 1) {
        if (tid < s) red[tid] += red[tid + s];
        __syncthreads();
    }
    float inv = 1.f / red[0];
    __syncthreads();
    if (tid < 128) {
        float acc = 0.f;
        for (int n = 0; n < NODE; ++n) acc += gate[n] * hb[(size_t)n * 128 + tid];
        out[g * 128 + tid] = acc * inv;
    }
}

extern "C" void kernel_launch(void* const* d_in, const int* in_sizes, int n_in,
                              void* d_out, int out_size, void* d_ws, size_t ws_size,
                              hipStream_t stream) {
    const float* x      = (const float*)d_in[0];
    const int*   src    = (const int*)d_in[1];
    const int*   dst    = (const int*)d_in[2];
    // d_in[3] node2graph: implicit (contiguous blocks of 1000)
    const float* W_src1 = (const float*)d_in[4];
    const float* b_src1 = (const float*)d_in[5];
    const float* W_dst1 = (const float*)d_in[6];
    const float* b_dst1 = (const float*)d_in[7];
    const float* attn1  = (const float*)d_in[8];
    const float* W_src2 = (const float*)d_in[9];
    const float* b_src2 = (const float*)d_in[10];
    const float* W_dst2 = (const float*)d_in[11];
    const float* b_dst2 = (const float*)d_in[12];
    const float* attn2  = (const float*)d_in[13];
    const float* gate_w = (const float*)d_in[14];
    const float* gate_b = (const float*)d_in[15];
    float* out = (float*)d_out;

    char* p = (char*)d_ws;
    auto alloc = [&](size_t bytes) -> void* {
        void* r = (void*)p;
        p += (bytes + 255) & ~(size_t)255;
        return r;
    };
    unsigned short* fs     = (unsigned short*)alloc((size_t)NN * 512 * 2);
    unsigned short* fd     = (unsigned short*)alloc((size_t)NN * 512 * 2);
    unsigned short* h1     = (unsigned short*)alloc((size_t)NN * 64 * 2);
    float*          h2     = (float*)alloc((size_t)NN * 128 * 4);
    unsigned short* x_bf   = (unsigned short*)alloc((size_t)NN * 128 * 2);
    unsigned short* Wt1s   = (unsigned short*)alloc((size_t)128 * 256 * 2);
    unsigned short* Wt1d   = (unsigned short*)alloc((size_t)128 * 256 * 2);
    unsigned short* Wt2s   = (unsigned short*)alloc((size_t)64 * 512 * 2);
    unsigned short* Wt2d   = (unsigned short*)alloc((size_t)64 * 512 * 2);
    int*            deg    = (int*)alloc((size_t)NN * 4);
    int*            rowptr = (int*)alloc((size_t)(NN + 1) * 4);
    int*            cursor = (int*)alloc((size_t)NN * 4);
    int*            csrc   = (int*)alloc((size_t)EE * 4);
    int*            bsum   = (int*)alloc(4096);

    // ---- dtype prep ----
    cvt_f32_bf16<<<(NN * 128 / 4 + 255) / 256, 256, 0, stream>>>(x, x_bf, NN * 128 / 4);
    wt_cvt<<<(128 * 256 + 255) / 256, 256, 0, stream>>>(W_src1, Wt1s, 128, 256);
    wt_cvt<<<(128 * 256 + 255) / 256, 256, 0, stream>>>(W_dst1, Wt1d, 128, 256);
    wt_cvt<<<(64 * 512 + 255) / 256, 256, 0, stream>>>(W_src2, Wt2s, 64, 512);
    wt_cvt<<<(64 * 512 + 255) / 256, 256, 0, stream>>>(W_dst2, Wt2d, 64, 512);

    // ---- CSR build (dst-indexed, src pre-gathered) ----
    hipMemsetAsync(deg, 0, (size_t)NN * 4, stream);
    count_deg<<<(EE + 255) / 256, 256, 0, stream>>>(dst, deg, EE);
    int nb = (NN + 255) / 256;
    scan1<<<nb, 256, 0, stream>>>(deg, bsum, NN);
    scan2<<<1, 64, 0, stream>>>(bsum, nb, rowptr, NN, EE);
    scan3<<<nb, 256, 0, stream>>>(deg, bsum, rowptr, cursor, NN);
    scatter_edges<<<(EE + 255) / 256, 256, 0, stream>>>(src, dst, cursor, csrc, EE);

    int rowtiles = (NN + 127) / 128; // 391

    // ---- layer 1 (D=64, HD=256, K=128) ----
    gemm_mfma<128><<<dim3(2, rowtiles), 256, 0, stream>>>(x_bf, Wt1s, b_src1, fs, NN, 256);
    gemm_mfma<128><<<dim3(2, rowtiles), 256, 0, stream>>>(x_bf, Wt1d, b_dst1, fd, NN, 256);
    gat_fused<64><<<2048, 256, 0, stream>>>(rowptr, csrc, fs, fd, attn1, h1, NN);

    // ---- layer 2 (D=128, HD=512, K=64) ----
    gemm_mfma<64><<<dim3(4, rowtiles), 256, 0, stream>>>(h1, Wt2s, b_src2, fs, NN, 512);
    gemm_mfma<64><<<dim3(4, rowtiles), 256, 0, stream>>>(h1, Wt2d, b_dst2, fd, NN, 512);
    gat_fused<128><<<2048, 256, 0, stream>>>(rowptr, csrc, fs, fd, attn2, h2, NN);

    // ---- global attention pooling ----
    pool_kernel<<<GG, 256, 0, stream>>>(h2, gate_w, gate_b, out);
}

// Round 12
// 356.628 us; speedup vs baseline: 1.1282x; 1.1282x over previous
//
#include <hip/hip_runtime.h>
#include <math.h>

#define NN 50000
#define GG 50
#define NODE 1000
#define EE 320000
#define HEADS 4

typedef __attribute__((ext_vector_type(8))) short short8;
typedef __attribute__((ext_vector_type(8))) __bf16 bf16x8;
typedef __attribute__((ext_vector_type(4))) float f32x4;

__device__ __forceinline__ unsigned short f2bf(float f) {
    unsigned int u = __float_as_uint(f);
    u = (u + 0x7fffu + ((u >> 16) & 1u)) >> 16;
    return (unsigned short)u;
}
__device__ __forceinline__ float bf2f(unsigned short s) {
    return __uint_as_float(((unsigned int)s) << 16);
}

// ---------------- merged dtype prep: x + all 4 weight transposes in ONE dispatch ----------------
__global__ void prep_cvt(const float* __restrict__ x, unsigned short* __restrict__ x_bf,
                         const float* __restrict__ W_src1, const float* __restrict__ W_dst1,
                         unsigned short* __restrict__ Wt1s, unsigned short* __restrict__ Wt1d,
                         const float* __restrict__ W_src2, const float* __restrict__ W_dst2,
                         unsigned short* __restrict__ Wt2s, unsigned short* __restrict__ Wt2d) {
    int i = blockIdx.x * 256 + threadIdx.x;
    int n4 = NN * 128 / 4;
    if (i < n4) {
        float4 f = *(const float4*)(x + (size_t)i * 4);
        ushort4 o;
        o.x = f2bf(f.x); o.y = f2bf(f.y); o.z = f2bf(f.z); o.w = f2bf(f.w);
        *(ushort4*)(x_bf + (size_t)i * 4) = o;
    }
    if (i < 256 * 128) {            // layer1 Wt[n][k]: n=i>>7, k=i&127
        int n = i >> 7, k = i & 127;
        Wt1s[i] = f2bf(W_src1[k * 256 + n]);
        Wt1d[i] = f2bf(W_dst1[k * 256 + n]);
    }
    if (i < 512 * 64) {             // layer2 Wt[n][k]: n=i>>6, k=i&63
        int n = i >> 6, k = i & 63;
        Wt2s[i] = f2bf(W_src2[k * 512 + n]);
        Wt2d[i] = f2bf(W_dst2[k * 512 + n]);
    }
}

// ---------------- CSR build ----------------
__global__ void count_deg(const int* __restrict__ dst, int* __restrict__ deg, int E_) {
    int i = blockIdx.x * 256 + threadIdx.x;
    if (i < E_) atomicAdd(&deg[dst[i]], 1);
}

__global__ void scan1(const int* __restrict__ deg, int* __restrict__ bsum, int Nn) {
    __shared__ int sh[256];
    int i = blockIdx.x * 256 + threadIdx.x;
    sh[threadIdx.x] = (i < Nn) ? deg[i] : 0;
    __syncthreads();
    for (int s = 128; s > 0; s >>= 1) {
        if (threadIdx.x < s) sh[threadIdx.x] += sh[threadIdx.x + s];
        __syncthreads();
    }
    if (threadIdx.x == 0) bsum[blockIdx.x] = sh[0];
}

// scan3 also computes its own exclusive prefix of bsum (kills the 1-thread scan2 kernel)
__global__ void scan3(const int* __restrict__ deg, const int* __restrict__ bsum,
                      int* __restrict__ rowptr, int* __restrict__ cursor, int Nn, int E_) {
    __shared__ int pr[256];
    __shared__ int sh[256];
    int bid = blockIdx.x;
    // exclusive prefix sum of bsum[0..bid)
    int pre = 0;
    for (int j = threadIdx.x; j < bid; j += 256) pre += bsum[j];
    pr[threadIdx.x] = pre;
    __syncthreads();
    for (int s = 128; s > 0; s >>= 1) {
        if (threadIdx.x < s) pr[threadIdx.x] += pr[threadIdx.x + s];
        __syncthreads();
    }
    int base = pr[0];
    __syncthreads();
    int i = bid * 256 + threadIdx.x;
    int v = (i < Nn) ? deg[i] : 0;
    sh[threadIdx.x] = v;
    __syncthreads();
    for (int s = 1; s < 256; s <<= 1) {
        int t = (threadIdx.x >= s) ? sh[threadIdx.x - s] : 0;
        __syncthreads();
        sh[threadIdx.x] += t;
        __syncthreads();
    }
    if (i < Nn) {
        int ex = sh[threadIdx.x] - v + base;
        rowptr[i] = ex;
        cursor[i] = ex;
    }
    if (bid == 0 && threadIdx.x == 0) rowptr[Nn] = E_;
}

// store src node id directly in CSR slot
__global__ void scatter_edges(const int* __restrict__ src, const int* __restrict__ dst,
                              int* __restrict__ cursor, int* __restrict__ csrc, int E_) {
    int i = blockIdx.x * 256 + threadIdx.x;
    if (i < E_) { int pos = atomicAdd(&cursor[dst[i]], 1); csrc[pos] = src[i]; }
}

// ---------------- bf16 MFMA GEMM, bf16 output, split-K staging (BK=64 -> 32 KB LDS) ----------------
// C[M,Ncols](bf16) = A[M,K](bf16) @ Wt[Ncols,K](bf16)^T + bias
template<int K>
__global__ __launch_bounds__(256)
void gemm_mfma(const unsigned short* __restrict__ A, const unsigned short* __restrict__ Wt,
               const float* __restrict__ bias, unsigned short* __restrict__ C,
               int M, int Ncols) {
    constexpr int BK = 64;             // K-slab
    __shared__ short A_lds[128 * BK];
    __shared__ short B_lds[128 * BK];
    constexpr int CH = BK / 8;         // 16B chunks per row (8)
    constexpr int ROWB = BK * 2;       // 128 B per LDS row
    int tid = threadIdx.x;
    int lane = tid & 63, wave = tid >> 6;
    int row0 = blockIdx.y * 128, col0 = blockIdx.x * 128;
    int wr = wave >> 1, wc = wave & 1;
    f32x4 acc[4][4] = {};

    for (int k0 = 0; k0 < K; k0 += BK) {
        if (k0) __syncthreads();       // all waves done reading previous slab
        for (int c = tid; c < 128 * CH; c += 256) {
            int r = c / CH, kc = c - r * CH;
            int gr = row0 + r; if (gr >= M) gr = M - 1;
            short8 v = *(const short8*)(A + (size_t)gr * K + k0 + kc * 8);
            *(short8*)((char*)A_lds + r * ROWB + ((kc * 16) ^ ((r & 7) << 4))) = v;
        }
        for (int c = tid; c < 128 * CH; c += 256) {
            int r = c / CH, kc = c - r * CH;
            short8 v = *(const short8*)(Wt + (size_t)(col0 + r) * K + k0 + kc * 8);
            *(short8*)((char*)B_lds + r * ROWB + ((kc * 16) ^ ((r & 7) << 4))) = v;
        }
        __syncthreads();

        #pragma unroll
        for (int ks = 0; ks < BK / 32; ++ks) {
            int kbyte = ks * 64 + ((lane >> 4) << 4);
            short8 a[4], b[4];
            #pragma unroll
            for (int m = 0; m < 4; ++m) {
                int r = wr * 64 + m * 16 + (lane & 15);
                a[m] = *(const short8*)((const char*)A_lds + r * ROWB + (kbyte ^ ((r & 7) << 4)));
            }
            #pragma unroll
            for (int n = 0; n < 4; ++n) {
                int r = wc * 64 + n * 16 + (lane & 15);
                b[n] = *(const short8*)((const char*)B_lds + r * ROWB + (kbyte ^ ((r & 7) << 4)));
            }
            #pragma unroll
            for (int m = 0; m < 4; ++m)
                #pragma unroll
                for (int n = 0; n < 4; ++n)
                    acc[m][n] = __builtin_amdgcn_mfma_f32_16x16x32_bf16(
                        __builtin_bit_cast(bf16x8, a[m]), __builtin_bit_cast(bf16x8, b[n]),
                        acc[m][n], 0, 0, 0);
        }
    }

    // epilogue: D mapping col=lane&15, row=(lane>>4)*4+q ; write bf16
    #pragma unroll
    for (int m = 0; m < 4; ++m) {
        int grb = row0 + wr * 64 + m * 16 + ((lane >> 4) << 2);
        #pragma unroll
        for (int q = 0; q < 4; ++q) {
            int gr = grb + q;
            if (gr < M) {
                #pragma unroll
                for (int n = 0; n < 4; ++n) {
                    int gc = col0 + wc * 64 + n * 16 + (lane & 15);
                    C[(size_t)gr * Ncols + gc] = f2bf(acc[m][n][q] + bias[gc]);
                }
            }
        }
    }
}

// ---------------- fused GATv2 edge phase (round-8 proven form): one wave per dst node ----------------
// Flash-style online softmax; fs[src] row read once per edge; fd[dst] once per node.
// Lane map: head = lane>>4, dims (lane&15)*VE .. +VE-1.
// D=64 -> hout bf16 [NN][64]; D=128 -> hout f32 [NN][128]
template<int D>
__global__ void gat_fused(const int* __restrict__ rowptr, const int* __restrict__ csrc,
                          const unsigned short* __restrict__ fs, const unsigned short* __restrict__ fd,
                          const float* __restrict__ attn, void* __restrict__ hout, int Nn) {
    int lane = threadIdx.x & 63;
    int wave = (blockIdx.x * blockDim.x + threadIdx.x) >> 6;
    int nw = (gridDim.x * blockDim.x) >> 6;
    constexpr int VE = D / 16;
    constexpr int HD = HEADS * D;
    int head = lane >> 4;
    int doff = (lane & 15) * VE;

    float at[VE];
    #pragma unroll
    for (int j = 0; j < VE; ++j) at[j] = attn[head * D + doff + j];

    for (int n = wave; n < Nn; n += nw) {
        int b = rowptr[n], e_ = rowptr[n + 1];
        float r[VE];
        if (b == e_) {
            #pragma unroll
            for (int k = 0; k < VE; ++k) r[k] = 0.f;
        } else {
            float fdf[VE];
            if constexpr (VE == 4) {
                ushort4 vd = *(const ushort4*)(fd + (size_t)n * HD + lane * 4);
                fdf[0] = bf2f(vd.x); fdf[1] = bf2f(vd.y); fdf[2] = bf2f(vd.z); fdf[3] = bf2f(vd.w);
            } else {
                short8 vd = *(const short8*)(fd + (size_t)n * HD + lane * 8);
                #pragma unroll
                for (int k = 0; k < 8; ++k) fdf[k] = bf2f((unsigned short)vd[k]);
            }
            float m = -INFINITY, l = 0.f;
            float acc[VE];
            #pragma unroll
            for (int k = 0; k < VE; ++k) acc[k] = 0.f;

            for (int j = b; j < e_; ++j) {
                int s = csrc[j];
                float fsf[VE];
                if constexpr (VE == 4) {
                    ushort4 vs = *(const ushort4*)(fs + (size_t)s * HD + lane * 4);
                    fsf[0] = bf2f(vs.x); fsf[1] = bf2f(vs.y); fsf[2] = bf2f(vs.z); fsf[3] = bf2f(vs.w);
                } else {
                    short8 vs = *(const short8*)(fs + (size_t)s * HD + lane * 8);
                    #pragma unroll
                    for (int k = 0; k < 8; ++k) fsf[k] = bf2f((unsigned short)vs[k]);
                }
                float p = 0.f;
                #pragma unroll
                for (int k = 0; k < VE; ++k) {
                    float v = fsf[k] + fdf[k];
                    v = v >= 0.f ? v : 0.2f * v;
                    p += v * at[k];
                }
                p += __shfl_xor(p, 1);
                p += __shfl_xor(p, 2);
                p += __shfl_xor(p, 4);
                p += __shfl_xor(p, 8);
                float mn = fmaxf(m, p);
                float sc = __expf(m - mn);   // 0 on first iter
                float pw = __expf(p - mn);
                l = l * sc + pw;
                #pragma unroll
                for (int k = 0; k < VE; ++k) acc[k] = acc[k] * sc + pw * fsf[k];
                m = mn;
            }
            float inv = 1.f / l;
            #pragma unroll
            for (int k = 0; k < VE; ++k) r[k] = acc[k] * inv;
        }
        #pragma unroll
        for (int k = 0; k < VE; ++k) {
            r[k] = fmaxf(r[k], __shfl_xor(r[k], 16));
            r[k] = fmaxf(r[k], __shfl_xor(r[k], 32));
        }
        if (lane < 16) {
            if constexpr (VE == 4) {
                ushort4 o;
                o.x = f2bf(r[0]); o.y = f2bf(r[1]); o.z = f2bf(r[2]); o.w = f2bf(r[3]);
                *(ushort4*)((unsigned short*)hout + (size_t)n * 64 + doff) = o;
            } else {
                float* hp = (float*)hout + (size_t)n * 128 + doff;
                *(float4*)hp = make_float4(r[0], r[1], r[2], r[3]);
                *(float4*)(hp + 4) = make_float4(r[4], r[5], r[6], r[7]);
            }
        }
    }
}

// ---------------- global attention pooling: one block per graph ----------------
__global__ void pool_kernel(const float* __restrict__ h2, const float* __restrict__ gate_w,
                            const float* __restrict__ gate_b, float* __restrict__ out) {
    __shared__ float gate[NODE];
    __shared__ float red[256];
    int g = blockIdx.x;
    int tid = threadIdx.x;
    const float* hb = h2 + (size_t)g * NODE * 128;
    float gb = gate_b[0];
    for (int n = tid; n < NODE; n += 256) {
        const float* r = hb + (size_t)n * 128;
        float acc = 0.f;
        #pragma unroll 8
        for (int k = 0; k < 128; ++k) acc += r[k] * gate_w[k];
        gate[n] = acc + gb;
    }
    __syncthreads();
    float m = -INFINITY;
    for (int n = tid; n < NODE; n += 256) m = fmaxf(m, gate[n]);
    red[tid] = m;
    __syncthreads();
    for (int s = 128; s > 0; s >>= 1) {
        if (tid < s) red[tid] = fmaxf(red[tid], red[tid + s]);
        __syncthreads();
    }
    m = red[0];
    __syncthreads();
    float ssum = 0.f;
    for (int n = tid; n < NODE; n += 256) {
        float e = __expf(gate[n] - m);
        gate[n] = e;
        ssum += e;
    }
    red[tid] = ssum;
    __syncthreads();
    for (int s = 128; s > 0; s >>= 1) {
        if (tid < s) red[tid] += red[tid + s];
        __syncthreads();
    }
    float inv = 1.f / red[0];
    __syncthreads();
    // weighted sum with all 256 threads: halves of the node range, then combine
    float acc = 0.f;
    int half = tid >> 7;          // 0 or 1
    int k = tid & 127;
    for (int n = half * 500; n < half * 500 + 500; ++n) acc += gate[n] * hb[(size_t)n * 128 + k];
    red[tid] = acc;
    __syncthreads();
    if (tid < 128) out[g * 128 + tid] = (red[tid] + red[tid + 128]) * inv;
}

extern "C" void kernel_launch(void* const* d_in, const int* in_sizes, int n_in,
                              void* d_out, int out_size, void* d_ws, size_t ws_size,
                              hipStream_t stream) {
    const float* x      = (const float*)d_in[0];
    const int*   src    = (const int*)d_in[1];
    const int*   dst    = (const int*)d_in[2];
    // d_in[3] node2graph: implicit (contiguous blocks of 1000)
    const float* W_src1 = (const float*)d_in[4];
    const float* b_src1 = (const float*)d_in[5];
    const float* W_dst1 = (const float*)d_in[6];
    const float* b_dst1 = (const float*)d_in[7];
    const float* attn1  = (const float*)d_in[8];
    const float* W_src2 = (const float*)d_in[9];
    const float* b_src2 = (const float*)d_in[10];
    const float* W_dst2 = (const float*)d_in[11];
    const float* b_dst2 = (const float*)d_in[12];
    const float* attn2  = (const float*)d_in[13];
    const float* gate_w = (const float*)d_in[14];
    const float* gate_b = (const float*)d_in[15];
    float* out = (float*)d_out;

    char* p = (char*)d_ws;
    auto alloc = [&](size_t bytes) -> void* {
        void* r = (void*)p;
        p += (bytes + 255) & ~(size_t)255;
        return r;
    };
    unsigned short* fs     = (unsigned short*)alloc((size_t)NN * 512 * 2);
    unsigned short* fd     = (unsigned short*)alloc((size_t)NN * 512 * 2);
    unsigned short* h1     = (unsigned short*)alloc((size_t)NN * 64 * 2);
    float*          h2     = (float*)alloc((size_t)NN * 128 * 4);
    unsigned short* x_bf   = (unsigned short*)alloc((size_t)NN * 128 * 2);
    unsigned short* Wt1s   = (unsigned short*)alloc((size_t)128 * 256 * 2);
    unsigned short* Wt1d   = (unsigned short*)alloc((size_t)128 * 256 * 2);
    unsigned short* Wt2s   = (unsigned short*)alloc((size_t)64 * 512 * 2);
    unsigned short* Wt2d   = (unsigned short*)alloc((size_t)64 * 512 * 2);
    int*            deg    = (int*)alloc((size_t)NN * 4);
    int*            rowptr = (int*)alloc((size_t)(NN + 1) * 4);
    int*            cursor = (int*)alloc((size_t)NN * 4);
    int*            csrc   = (int*)alloc((size_t)EE * 4);
    int*            bsum   = (int*)alloc(4096);

    // ---- merged dtype prep (1 dispatch) ----
    prep_cvt<<<(NN * 128 / 4 + 255) / 256, 256, 0, stream>>>(
        x, x_bf, W_src1, W_dst1, Wt1s, Wt1d, W_src2, W_dst2, Wt2s, Wt2d);

    // ---- CSR build (dst-indexed, src pre-gathered); scan2 folded into scan3 ----
    hipMemsetAsync(deg, 0, (size_t)NN * 4, stream);
    count_deg<<<(EE + 255) / 256, 256, 0, stream>>>(dst, deg, EE);
    int nb = (NN + 255) / 256;
    scan1<<<nb, 256, 0, stream>>>(deg, bsum, NN);
    scan3<<<nb, 256, 0, stream>>>(deg, bsum, rowptr, cursor, NN, EE);
    scatter_edges<<<(EE + 255) / 256, 256, 0, stream>>>(src, dst, cursor, csrc, EE);

    int rowtiles = (NN + 127) / 128; // 391

    // ---- layer 1 (D=64, HD=256, K=128) ----
    gemm_mfma<128><<<dim3(2, rowtiles), 256, 0, stream>>>(x_bf, Wt1s, b_src1, fs, NN, 256);
    gemm_mfma<128><<<dim3(2, rowtiles), 256, 0, stream>>>(x_bf, Wt1d, b_dst1, fd, NN, 256);
    gat_fused<64><<<2048, 256, 0, stream>>>(rowptr, csrc, fs, fd, attn1, h1, NN);

    // ---- layer 2 (D=128, HD=512, K=64) ----
    gemm_mfma<64><<<dim3(4, rowtiles), 256, 0, stream>>>(h1, Wt2s, b_src2, fs, NN, 512);
    gemm_mfma<64><<<dim3(4, rowtiles), 256, 0, stream>>>(h1, Wt2d, b_dst2, fd, NN, 512);
    gat_fused<128><<<2048, 256, 0, stream>>>(rowptr, csrc, fs, fd, attn2, h2, NN);

    // ---- global attention pooling ----
    pool_kernel<<<GG, 256, 0, stream>>>(h2, gate_w, gate_b, out);
}